// Round 3
// baseline (319.877 us; speedup 1.0000x reference)
//
#include <hip/hip_runtime.h>

// Deformable depthwise 3x3 conv, B=8 C=256 H=W=96, fp32.
// R5: full-plane LDS, 2 bar/chan, 166 us. R6: launch_bounds(,6) -> scratch
//     spill catastrophe, 604 us. R7: gload_lds dbuf, 1 bar/chan, 179 us.
// R7 post-mortem: (a) 6-wave blocks quantize against the 128-reg/16-wave
//     budget -> only 2 blocks/CU resident (Occ 26%); (b) __syncthreads
//     drains vmcnt(0) -> each phase eats ~900cy HBM latency of the pf it
//     just issued. LDS pipe (~86 us/CU incl. 51 us conflicts) only ~50% fed.
// R8: (a) 3-wave blocks (NT=192, TH=2): floor(16/3)=5 blocks=15 waves,
//         12 blocks/CU grid -> smooth tail. CAP=16, 3 bufs = 18.4 KB.
//     (b) depth-2 counted-vmcnt pipeline (T3/T4): phase =
//         {vmcnt(2); s_barrier; gather buf[cc%3]; store; issue pf(cc+2)}.
//         Wait targets loads issued TWO phases ago -> no drain stall.
//         Uniform 2 gload_lds/phase (clamped global idx, lane-linear LDS
//         slot) so vmcnt(2) is exact per wave. pf(cc+2) writes
//         buf[(cc-1)%3] whose reads finished before this phase's barrier.
// Invariants to watch: WRITE_SIZE 73.7 MB (spill tripwire),
//     SQ_LDS_BANK_CONFLICT ~3.171e7 (gather pattern unchanged).

constexpr int B_ = 8, C_ = 256, H_ = 96, W_ = 96;
constexpr int HW_ = H_ * W_;
constexpr int TH = 2;              // pixel rows per block
constexpr int NT = TH * W_;        // 192 threads = 3 waves
constexpr int CSPLIT = 8;
constexpr int CPB = C_ / CSPLIT;   // 32 channels per block
constexpr int CAP = 16;            // window rows per buffer (typ. ~10-11)
constexpr int CAPE = CAP * W_;     // 1536 floats = 6144 B per buffer
constexpr int NCH = CAPE / 4;      // 384 float4 chunks = 2*NT exactly

__device__ __forceinline__ void gl_lds16(const float* g, float* l) {
    // async global->LDS, 16B/lane; LDS dest = wave-uniform base + lane*16.
    __builtin_amdgcn_global_load_lds(
        (const __attribute__((address_space(1))) void*)g,
        (__attribute__((address_space(3))) void*)l, 16, 0, 0);
}

__global__ __launch_bounds__(NT, 4) void deform_dw_conv(
    const float* __restrict__ x, const float* __restrict__ off,
    const float* __restrict__ wgt, const float* __restrict__ bias,
    float* __restrict__ out)
{
    __shared__ float lx[3 * CAPE];   // triple buffer, dense 96-dword rows
    __shared__ int s_rmin, s_rmax;

    const int tid  = threadIdx.x;
    const int r    = tid / W_;
    const int wcol = tid - r * W_;
    const int h    = blockIdx.x * TH + r;
    const int b    = blockIdx.y;
    const int c0   = blockIdx.z * CPB;

    if (tid == 0) { s_rmin = H_; s_rmax = -1; }
    __syncthreads();

    const float* offp = off + (size_t)b * 18 * HW_ + (size_t)h * W_ + wcol;

    // Per-(pixel,tap): 4 weights pre-permuted onto loaded positions
    // [0]=(yc,xc) [1]=(yc,xc+1) [2]=(yc+1,xc) [3]=(yc+1,xc+1); validity
    // folded into weights so invalid corners multiply by 0.
    float cw[9][4];
    int lofs[9];                     // plane offset yc*96+xc (abs for now)
    int myrmin = H_, myrmax = -1;

#pragma unroll
    for (int kk = 0; kk < 9; ++kk) {
        const int i = kk / 3, j = kk % 3;
        const float py = (float)(h - 1 + i) + offp[(2 * kk) * HW_];
        const float px = (float)(wcol - 1 + j) + offp[(2 * kk + 1) * HW_];
        const float fy = floorf(py), fx = floorf(px);
        const float wy = py - fy, wx = px - fx;
        const int y0 = (int)fy, x0 = (int)fx;
        const bool vy0 = (unsigned)y0 < (unsigned)H_;
        const bool vy1 = (unsigned)(y0 + 1) < (unsigned)H_;
        const bool vx0 = (unsigned)x0 < (unsigned)W_;
        const bool vx1 = (unsigned)(x0 + 1) < (unsigned)W_;
        const float w00 = (vy0 && vx0) ? (1.f - wy) * (1.f - wx) : 0.f;
        const float w01 = (vy0 && vx1) ? (1.f - wy) * wx : 0.f;
        const float w10 = (vy1 && vx0) ? wy * (1.f - wx) : 0.f;
        const float w11 = (vy1 && vx1) ? wy * wx : 0.f;
        const int yc = min(max(y0, 0), H_ - 2);
        const int xc = min(max(x0, 0), W_ - 2);
        const bool rs = (y0 == yc);
        const bool cs = (x0 == xc);
        cw[kk][0] = rs ? (cs ? w00 : w01) : (cs ? w10 : w11);
        cw[kk][1] = rs ? (cs ? w01 : w00) : (cs ? w11 : w10);
        cw[kk][2] = rs ? (cs ? w10 : w11) : (cs ? w00 : w01);
        cw[kk][3] = rs ? (cs ? w11 : w10) : (cs ? w01 : w00);
        lofs[kk] = yc * W_ + xc;
        myrmin = min(myrmin, yc);
        myrmax = max(myrmax, yc);
    }
    atomicMin(&s_rmin, myrmin);
    atomicMax(&s_rmax, myrmax);
    __syncthreads();
    const int rmin  = s_rmin;
    const int nrows = s_rmax + 2 - rmin;   // rows [rmin, rmax+1]
    const int pix   = h * W_ + wcol;

    if (nrows > CAP) {
        // Cold correctness path (P~0 on N(0,1) offsets): direct global
        // gather; clamped coords always in-bounds, zero weights neutralize
        // invalid corners. Block-uniform branch; no barriers after this.
        const float* xp = x + (size_t)(b * C_ + c0) * HW_;
        float* op = out + (size_t)(b * C_ + c0) * HW_ + pix;
        for (int cc = 0; cc < CPB; ++cc) {
            float acc = 0.f;
#pragma unroll
            for (int kk = 0; kk < 9; ++kk) {
                const float* q = xp + lofs[kk];
                float s = cw[kk][0] * q[0];
                s = fmaf(cw[kk][1], q[1], s);
                s = fmaf(cw[kk][2], q[W_], s);
                s = fmaf(cw[kk][3], q[W_ + 1], s);
                acc = fmaf(wgt[(c0 + cc) * 9 + kk], s, acc);
            }
            *op = acc + bias[c0 + cc];
            xp += HW_; op += HW_;
        }
        return;
    }

#pragma unroll
    for (int kk = 0; kk < 9; ++kk) lofs[kk] -= rmin * W_;

    // Staging: n4 float4 chunks (<= 384 = 2*NT), linear in global and LDS.
    // Uniform 2 gload_lds per stage: global chunk index CLAMPED (duplicate
    // loads of the last chunk), LDS slot stays lane-linear (tid, tid+NT
    // both < NCH) so writes land in unused-but-in-buffer rows. Uniform
    // issue count is what makes the counted vmcnt exact for every wave.
    const int n4 = nrows * (W_ / 4);
    const int g0 = min(tid, n4 - 1);
    const int g1 = min(tid + NT, n4 - 1);

    const float* xwin = x + (size_t)(b * C_ + c0) * HW_ + rmin * W_;

    // Prologue: stage c0 -> buf0, c0+1 -> buf1 (both stay in flight).
    gl_lds16(xwin + 4 * g0, &lx[4 * tid]);
    gl_lds16(xwin + 4 * g1, &lx[4 * (tid + NT)]);
    gl_lds16(xwin + HW_ + 4 * g0, &lx[CAPE + 4 * tid]);
    gl_lds16(xwin + HW_ + 4 * g1, &lx[CAPE + 4 * (tid + NT)]);

    float* outp = out + (size_t)(b * C_ + c0) * HW_ + pix;
    const float* wp = wgt + c0 * 9;
    const float* bp = bias + c0;

    int pb  = 0;                 // read buffer base (floats)
    int pfb = 2 * CAPE;          // prefetch dest base = buf[(cc+2)%3]

#pragma unroll 1
    for (int cc = 0; cc < CPB; ++cc) {
        // Wait until <=2 VMEM outstanding: the 2 newest are pf(cc+1)'s
        // pair -> pf(cc) (and any older store) has landed. Then barrier.
        asm volatile("s_waitcnt vmcnt(2)\n\ts_barrier" ::: "memory");

        float acc = 0.f;
#pragma unroll
        for (int kk = 0; kk < 9; ++kk) {
            float2 A, Bv;                       // ds_read2_b32 pairs
            __builtin_memcpy(&A,  &lx[pb + lofs[kk]],      sizeof(float2));
            __builtin_memcpy(&Bv, &lx[pb + lofs[kk] + W_], sizeof(float2));
            float s = cw[kk][0] * A.x;
            s = fmaf(cw[kk][1], A.y,  s);
            s = fmaf(cw[kk][2], Bv.x, s);
            s = fmaf(cw[kk][3], Bv.y, s);
            acc = fmaf(wp[cc * 9 + kk], s, acc);
        }
        *outp = acc + bp[cc];
        outp += HW_;

        // Issue pf(cc+2) into buf[(cc-1)%3] — its last reads completed
        // before the barrier above (all waves). Channel clamped so the
        // issue count stays uniform through the final phases (the dup
        // lands in a buffer that is never read again).
        {
            const int cch = min(cc + 2, CPB - 1);
            const float* nxt = xwin + (size_t)cch * HW_;
            gl_lds16(nxt + 4 * g0, &lx[pfb + 4 * tid]);
            gl_lds16(nxt + 4 * g1, &lx[pfb + 4 * (tid + NT)]);
        }

        pb  += CAPE; if (pb  == 3 * CAPE) pb  = 0;
        pfb += CAPE; if (pfb == 3 * CAPE) pfb = 0;
    }
}

extern "C" void kernel_launch(void* const* d_in, const int* in_sizes, int n_in,
                              void* d_out, int out_size, void* d_ws, size_t ws_size,
                              hipStream_t stream) {
    const float* x    = (const float*)d_in[0];
    const float* off  = (const float*)d_in[1];
    const float* w    = (const float*)d_in[2];
    const float* bias = (const float*)d_in[3];
    float* out        = (float*)d_out;
    dim3 grid(H_ / TH, B_, CSPLIT);
    deform_dw_conv<<<grid, NT, 0, stream>>>(x, off, w, bias, out);
}

// Round 4
// 249.324 us; speedup vs baseline: 1.2830x; 1.2830x over previous
//
#include <hip/hip_runtime.h>

// Deformable depthwise 3x3 conv, B=8 C=256 H=W=96, fp32.
// R5: full-plane LDS, 2 bar/chan, reg prefetch, NO min-waves bound: 166 us.
// R6: launch_bounds(,6) -> scratch spill, 604 us. R7: gload_lds dbuf 179 us.
// R8: counted-vmcnt asm pipeline -> cw[9][4] spilled AGAIN (WRITE +80MB =
//     3072 blk x 192 thr x 36 dwords), 225 us. Lesson: pipeline cleverness
//     keeps paying its register cost as HBM scratch traffic. Revert rhythm.
// Cost model per CU: 20.7k ds_read2 instrs (~83k cy) + 124k conflict cy
//     (SQ_LDS_BANK_CONFLICT 3.171e7, invariant R5/R7/R8) = ~86 us LDS pipe
//     of the 166 us wall -> LDS-pipe-bound, conflicts 60% of it.
// R9: channel-interleaved float4 layout. Offsets are channel-invariant, so
//     stage 4 channels per position: lx4[pos] = {c0,c1,c2,c3}. One
//     ds_read_b128 per corner serves 4 channels -> per-px-ch LDS instrs
//     18 -> 9 (bytes equal; floor 2.7GB ~= 35 us/CU). Bank unit becomes a
//     4-bank quad (quad = pos%8): jitter imbalance ~8->11 cy per instr vs
//     2->4.5 before; conflict opportunities per dword / 4.
//     Staging reg-staged (transpose): 4 coalesced dword loads + 1 b128
//     write per position (write quads spread -> conflict-free).
//     8 phases instead of 32 -> barrier/drain overhead / 4.
//     Plain __syncthreads only, __launch_bounds__(NT) only (anti-spill).
// Tripwires: WRITE_SIZE must stay 73728 KB; predict BANK_CONFLICT -> ~1e7.

constexpr int B_ = 8, C_ = 256, H_ = 96, W_ = 96;
constexpr int HW_ = H_ * W_;
constexpr int TH = 4;              // pixel rows per block
constexpr int NT = TH * W_;        // 384 threads = 6 waves
constexpr int CSPLIT = 8;
constexpr int CPB = C_ / CSPLIT;   // 32 channels per block
constexpr int G4 = CPB / 4;        // 8 groups of 4 interleaved channels
constexpr int CAP = 24;            // window rows (typ ~13-15 used)
constexpr int NPOS = CAP * W_;     // 2304 positions = 36864 B as float4
constexpr int NL = NPOS / NT;      // 6 staging chunks per thread max

__global__ __launch_bounds__(NT) void deform_dw_conv(
    const float* __restrict__ x, const float* __restrict__ off,
    const float* __restrict__ wgt, const float* __restrict__ bias,
    float* __restrict__ out)
{
    __shared__ float4 lx4[NPOS];   // [pos] = 4 channels at spatial pos
    __shared__ int s_rmin, s_rmax;

    const int tid  = threadIdx.x;
    const int r    = tid / W_;
    const int wcol = tid - r * W_;
    const int h    = blockIdx.x * TH + r;
    const int b    = blockIdx.y;
    const int c0   = blockIdx.z * CPB;

    if (tid == 0) { s_rmin = H_; s_rmax = -1; }
    __syncthreads();

    const float* offp = off + (size_t)b * 18 * HW_ + (size_t)h * W_ + wcol;

    // Per-(pixel,tap): 4 weights pre-permuted onto loaded positions
    // [0]=(yc,xc) [1]=(yc,xc+1) [2]=(yc+1,xc) [3]=(yc+1,xc+1); validity
    // folded into weights so invalid corners multiply by 0.
    float cw[9][4];
    int lofs[9];
    int myrmin = H_, myrmax = -1;

#pragma unroll
    for (int kk = 0; kk < 9; ++kk) {
        const int i = kk / 3, j = kk % 3;
        const float py = (float)(h - 1 + i) + offp[(2 * kk) * HW_];
        const float px = (float)(wcol - 1 + j) + offp[(2 * kk + 1) * HW_];
        const float fy = floorf(py), fx = floorf(px);
        const float wy = py - fy, wx = px - fx;
        const int y0 = (int)fy, x0 = (int)fx;
        const bool vy0 = (unsigned)y0 < (unsigned)H_;
        const bool vy1 = (unsigned)(y0 + 1) < (unsigned)H_;
        const bool vx0 = (unsigned)x0 < (unsigned)W_;
        const bool vx1 = (unsigned)(x0 + 1) < (unsigned)W_;
        const float w00 = (vy0 && vx0) ? (1.f - wy) * (1.f - wx) : 0.f;
        const float w01 = (vy0 && vx1) ? (1.f - wy) * wx : 0.f;
        const float w10 = (vy1 && vx0) ? wy * (1.f - wx) : 0.f;
        const float w11 = (vy1 && vx1) ? wy * wx : 0.f;
        const int yc = min(max(y0, 0), H_ - 2);
        const int xc = min(max(x0, 0), W_ - 2);
        const bool rs = (y0 == yc);
        const bool cs = (x0 == xc);
        cw[kk][0] = rs ? (cs ? w00 : w01) : (cs ? w10 : w11);
        cw[kk][1] = rs ? (cs ? w01 : w00) : (cs ? w11 : w10);
        cw[kk][2] = rs ? (cs ? w10 : w11) : (cs ? w00 : w01);
        cw[kk][3] = rs ? (cs ? w11 : w10) : (cs ? w01 : w00);
        lofs[kk] = yc * W_ + xc;
        myrmin = min(myrmin, yc);
        myrmax = max(myrmax, yc);
    }
    atomicMin(&s_rmin, myrmin);
    atomicMax(&s_rmax, myrmax);
    __syncthreads();
    const int rmin  = s_rmin;
    const int nrows = s_rmax + 2 - rmin;   // rows [rmin, rmax+1]
    const int pix   = h * W_ + wcol;

    if (nrows > CAP) {
        // Cold correctness path (P~0 on N(0,1) offsets): direct global
        // gather; clamped coords always in-bounds, zero weights neutralize
        // invalid corners. Block-uniform branch; no barriers after this.
        const float* xp = x + (size_t)(b * C_ + c0) * HW_;
        float* op = out + (size_t)(b * C_ + c0) * HW_ + pix;
        for (int cc = 0; cc < CPB; ++cc) {
            float acc = 0.f;
#pragma unroll
            for (int kk = 0; kk < 9; ++kk) {
                const float* q = xp + lofs[kk];
                float s = cw[kk][0] * q[0];
                s = fmaf(cw[kk][1], q[1], s);
                s = fmaf(cw[kk][2], q[W_], s);
                s = fmaf(cw[kk][3], q[W_ + 1], s);
                acc = fmaf(wgt[(c0 + cc) * 9 + kk], s, acc);
            }
            *op = acc + bias[c0 + cc];
            xp += HW_; op += HW_;
        }
        return;
    }

#pragma unroll
    for (int kk = 0; kk < 9; ++kk) lofs[kk] -= rmin * W_;

    const int P = nrows * W_;              // active positions (<= NPOS)
    const float* xbase = x + (size_t)(b * C_ + c0) * HW_ + rmin * W_;
    float* outb = out + (size_t)(b * C_ + c0) * HW_ + pix;

#pragma unroll 1
    for (int g = 0; g < G4; ++g) {
        const float* p0 = xbase + (size_t)(4 * g) * HW_;
        const float* p1 = p0 + HW_;
        const float* p2 = p1 + HW_;
        const float* p3 = p2 + HW_;

        // Reg-stage the 4 planes, transposed to position-major float4.
        // Loads coalesced (consecutive lanes -> consecutive dwords/plane);
        // issued before barrier1 so latency overlaps the previous gather
        // tail + barrier wait (R5 rhythm).
        float4 pf[NL];
#pragma unroll
        for (int i = 0; i < NL; ++i) {
            const int p = tid + i * NT;
            if (p < P) {
                pf[i].x = p0[p]; pf[i].y = p1[p];
                pf[i].z = p2[p]; pf[i].w = p3[p];
            }
        }
        __syncthreads();               // previous gather done; LDS free
#pragma unroll
        for (int i = 0; i < NL; ++i) {
            const int p = tid + i * NT;
            if (p < P) lx4[p] = pf[i]; // ds_write_b128, quads spread
        }
        __syncthreads();               // staged & visible

        const float* wg = wgt + (size_t)(c0 + 4 * g) * 9;
        float ax = 0.f, ay = 0.f, az = 0.f, aw = 0.f;
#pragma unroll
        for (int kk = 0; kk < 9; ++kk) {
            const int q = lofs[kk];
            const float4 A0 = lx4[q];
            const float4 A1 = lx4[q + 1];
            const float4 B0 = lx4[q + W_];
            const float4 B1 = lx4[q + W_ + 1];
            const float c0w = cw[kk][0], c1w = cw[kk][1];
            const float c2w = cw[kk][2], c3w = cw[kk][3];
            float sx = c0w * A0.x; sx = fmaf(c1w, A1.x, sx);
            sx = fmaf(c2w, B0.x, sx); sx = fmaf(c3w, B1.x, sx);
            float sy = c0w * A0.y; sy = fmaf(c1w, A1.y, sy);
            sy = fmaf(c2w, B0.y, sy); sy = fmaf(c3w, B1.y, sy);
            float sz = c0w * A0.z; sz = fmaf(c1w, A1.z, sz);
            sz = fmaf(c2w, B0.z, sz); sz = fmaf(c3w, B1.z, sz);
            float sw = c0w * A0.w; sw = fmaf(c1w, A1.w, sw);
            sw = fmaf(c2w, B0.w, sw); sw = fmaf(c3w, B1.w, sw);
            ax = fmaf(wg[kk],      sx, ax);
            ay = fmaf(wg[9 + kk],  sy, ay);
            az = fmaf(wg[18 + kk], sz, az);
            aw = fmaf(wg[27 + kk], sw, aw);
        }
        const int cg = c0 + 4 * g;
        outb[(size_t)(4 * g + 0) * HW_] = ax + bias[cg + 0];
        outb[(size_t)(4 * g + 1) * HW_] = ay + bias[cg + 1];
        outb[(size_t)(4 * g + 2) * HW_] = az + bias[cg + 2];
        outb[(size_t)(4 * g + 3) * HW_] = aw + bias[cg + 3];
    }
}

extern "C" void kernel_launch(void* const* d_in, const int* in_sizes, int n_in,
                              void* d_out, int out_size, void* d_ws, size_t ws_size,
                              hipStream_t stream) {
    const float* x    = (const float*)d_in[0];
    const float* off  = (const float*)d_in[1];
    const float* w    = (const float*)d_in[2];
    const float* bias = (const float*)d_in[3];
    float* out        = (float*)d_out;
    dim3 grid(H_ / TH, B_, CSPLIT);
    deform_dw_conv<<<grid, NT, 0, stream>>>(x, off, w, bias, out);
}

// Round 5
// 220.820 us; speedup vs baseline: 1.4486x; 1.1291x over previous
//
#include <hip/hip_runtime.h>

// Deformable depthwise 3x3 conv, B=8 C=256 H=W=96, fp32.
// Ladder: R5 166us (full-plane LDS, scalar gather) -> R9 152us
//   (channel-interleaved float4 gather: conflicts 3.17e7 -> 1.46e7,
//   per-px-ch LDS instrs 18 -> 9). R6/R8 lessons: min-waves bounds and
//   asm-barrier pipelines push cw[9][4] into HBM scratch -> never again.
// R9 post-mortem: LDS pipe ~75us of 152us wall; VALU 23%; stall-bound.
//   (a) staging loads issue at top of phase, overlap only barrier1 wait
//       -> exposed global latency every phase;
//   (b) CAP=24 -> 37376B LDS -> 4 blocks/CU, Occ 16.6%.
// R10: (a) T14 issue-early/write-late: issue pf(g+1) BEFORE gather(g);
//          the ~2600cy gather hides load latency; barrier1's vmcnt(0)
//          drain becomes free. pf[5] lives across gather (+20 VGPR, ok).
//      (b) CAP 24 -> 20 (window typ ~14 rows; >=5.5-sigma tail -> fallback
//          path): 30720B -> 5 blocks/CU.
// Tripwires: WRITE_SIZE == 73728 KB exactly (scratch spill detector);
//   SQ_LDS_BANK_CONFLICT ~1.46e7 (gather pattern unchanged).

constexpr int B_ = 8, C_ = 256, H_ = 96, W_ = 96;
constexpr int HW_ = H_ * W_;
constexpr int TH = 4;              // pixel rows per block
constexpr int NT = TH * W_;        // 384 threads = 6 waves
constexpr int CSPLIT = 8;
constexpr int CPB = C_ / CSPLIT;   // 32 channels per block
constexpr int G4 = CPB / 4;        // 8 groups of 4 interleaved channels
constexpr int CAP = 20;            // window rows (typ ~14 used)
constexpr int NPOS = CAP * W_;     // 1920 positions = 30720 B as float4
constexpr int NL = NPOS / NT;      // 5 staging chunks per thread max

__global__ __launch_bounds__(NT) void deform_dw_conv(
    const float* __restrict__ x, const float* __restrict__ off,
    const float* __restrict__ wgt, const float* __restrict__ bias,
    float* __restrict__ out)
{
    __shared__ float4 lx4[NPOS];   // [pos] = 4 channels at spatial pos
    __shared__ int s_rmin, s_rmax;

    const int tid  = threadIdx.x;
    const int r    = tid / W_;
    const int wcol = tid - r * W_;
    const int h    = blockIdx.x * TH + r;
    const int b    = blockIdx.y;
    const int c0   = blockIdx.z * CPB;

    if (tid == 0) { s_rmin = H_; s_rmax = -1; }
    __syncthreads();

    const float* offp = off + (size_t)b * 18 * HW_ + (size_t)h * W_ + wcol;

    // Per-(pixel,tap): 4 weights pre-permuted onto loaded positions
    // [0]=(yc,xc) [1]=(yc,xc+1) [2]=(yc+1,xc) [3]=(yc+1,xc+1); validity
    // folded into weights so invalid corners multiply by 0.
    float cw[9][4];
    int lofs[9];
    int myrmin = H_, myrmax = -1;

#pragma unroll
    for (int kk = 0; kk < 9; ++kk) {
        const int i = kk / 3, j = kk % 3;
        const float py = (float)(h - 1 + i) + offp[(2 * kk) * HW_];
        const float px = (float)(wcol - 1 + j) + offp[(2 * kk + 1) * HW_];
        const float fy = floorf(py), fx = floorf(px);
        const float wy = py - fy, wx = px - fx;
        const int y0 = (int)fy, x0 = (int)fx;
        const bool vy0 = (unsigned)y0 < (unsigned)H_;
        const bool vy1 = (unsigned)(y0 + 1) < (unsigned)H_;
        const bool vx0 = (unsigned)x0 < (unsigned)W_;
        const bool vx1 = (unsigned)(x0 + 1) < (unsigned)W_;
        const float w00 = (vy0 && vx0) ? (1.f - wy) * (1.f - wx) : 0.f;
        const float w01 = (vy0 && vx1) ? (1.f - wy) * wx : 0.f;
        const float w10 = (vy1 && vx0) ? wy * (1.f - wx) : 0.f;
        const float w11 = (vy1 && vx1) ? wy * wx : 0.f;
        const int yc = min(max(y0, 0), H_ - 2);
        const int xc = min(max(x0, 0), W_ - 2);
        const bool rs = (y0 == yc);
        const bool cs = (x0 == xc);
        cw[kk][0] = rs ? (cs ? w00 : w01) : (cs ? w10 : w11);
        cw[kk][1] = rs ? (cs ? w01 : w00) : (cs ? w11 : w10);
        cw[kk][2] = rs ? (cs ? w10 : w11) : (cs ? w00 : w01);
        cw[kk][3] = rs ? (cs ? w11 : w10) : (cs ? w01 : w00);
        lofs[kk] = yc * W_ + xc;
        myrmin = min(myrmin, yc);
        myrmax = max(myrmax, yc);
    }
    atomicMin(&s_rmin, myrmin);
    atomicMax(&s_rmax, myrmax);
    __syncthreads();
    const int rmin  = s_rmin;
    const int nrows = s_rmax + 2 - rmin;   // rows [rmin, rmax+1]
    const int pix   = h * W_ + wcol;

    if (nrows > CAP) {
        // Cold correctness path (>=5.5-sigma block event): direct global
        // gather; clamped coords always in-bounds, zero weights neutralize
        // invalid corners. Block-uniform branch; no barriers after this.
        const float* xp = x + (size_t)(b * C_ + c0) * HW_;
        float* op = out + (size_t)(b * C_ + c0) * HW_ + pix;
        for (int cc = 0; cc < CPB; ++cc) {
            float acc = 0.f;
#pragma unroll
            for (int kk = 0; kk < 9; ++kk) {
                const float* q = xp + lofs[kk];
                float s = cw[kk][0] * q[0];
                s = fmaf(cw[kk][1], q[1], s);
                s = fmaf(cw[kk][2], q[W_], s);
                s = fmaf(cw[kk][3], q[W_ + 1], s);
                acc = fmaf(wgt[(c0 + cc) * 9 + kk], s, acc);
            }
            *op = acc + bias[c0 + cc];
            xp += HW_; op += HW_;
        }
        return;
    }

#pragma unroll
    for (int kk = 0; kk < 9; ++kk) lofs[kk] -= rmin * W_;

    const int P = nrows * W_;              // active positions (<= NPOS)
    const float* xbase = x + (size_t)(b * C_ + c0) * HW_ + rmin * W_;
    float* outb = out + (size_t)(b * C_ + c0) * HW_ + pix;

    // Transposed reg-staging for one 4-channel group.
    float4 pf[NL];
    auto issue = [&](int g) {
        const float* p0 = xbase + (size_t)(4 * g) * HW_;
        const float* p1 = p0 + HW_;
        const float* p2 = p1 + HW_;
        const float* p3 = p2 + HW_;
#pragma unroll
        for (int i = 0; i < NL; ++i) {
            const int p = tid + i * NT;
            if (p < P) {
                pf[i].x = p0[p]; pf[i].y = p1[p];
                pf[i].z = p2[p]; pf[i].w = p3[p];
            }
        }
    };
    auto commit = [&]() {
#pragma unroll
        for (int i = 0; i < NL; ++i) {
            const int p = tid + i * NT;
            if (p < P) lx4[p] = pf[i];     // ds_write_b128, quads spread
        }
    };

    // Prologue: stage group 0 (LDS untouched yet -> no pre-barrier).
    issue(0);
    commit();
    __syncthreads();

#pragma unroll 1
    for (int g = 0; g < G4; ++g) {
        // T14 issue-early: next group's global loads start NOW and have
        // the whole gather below (~2600 cy) to land. The vmcnt(0) inside
        // the next __syncthreads is then free.
        if (g + 1 < G4) issue(g + 1);

        const float* wg = wgt + (size_t)(c0 + 4 * g) * 9;
        float ax = 0.f, ay = 0.f, az = 0.f, aw = 0.f;
#pragma unroll
        for (int kk = 0; kk < 9; ++kk) {
            const int q = lofs[kk];
            const float4 A0 = lx4[q];
            const float4 A1 = lx4[q + 1];
            const float4 B0 = lx4[q + W_];
            const float4 B1 = lx4[q + W_ + 1];
            const float c0w = cw[kk][0], c1w = cw[kk][1];
            const float c2w = cw[kk][2], c3w = cw[kk][3];
            float sx = c0w * A0.x; sx = fmaf(c1w, A1.x, sx);
            sx = fmaf(c2w, B0.x, sx); sx = fmaf(c3w, B1.x, sx);
            float sy = c0w * A0.y; sy = fmaf(c1w, A1.y, sy);
            sy = fmaf(c2w, B0.y, sy); sy = fmaf(c3w, B1.y, sy);
            float sz = c0w * A0.z; sz = fmaf(c1w, A1.z, sz);
            sz = fmaf(c2w, B0.z, sz); sz = fmaf(c3w, B1.z, sz);
            float sw = c0w * A0.w; sw = fmaf(c1w, A1.w, sw);
            sw = fmaf(c2w, B0.w, sw); sw = fmaf(c3w, B1.w, sw);
            ax = fmaf(wg[kk],      sx, ax);
            ay = fmaf(wg[9 + kk],  sy, ay);
            az = fmaf(wg[18 + kk], sz, az);
            aw = fmaf(wg[27 + kk], sw, aw);
        }
        const int cg = c0 + 4 * g;
        outb[(size_t)(4 * g + 0) * HW_] = ax + bias[cg + 0];
        outb[(size_t)(4 * g + 1) * HW_] = ay + bias[cg + 1];
        outb[(size_t)(4 * g + 2) * HW_] = az + bias[cg + 2];
        outb[(size_t)(4 * g + 3) * HW_] = aw + bias[cg + 3];

        if (g + 1 < G4) {
            __syncthreads();           // readers of group g done
            commit();                  // write-late: pf -> LDS
            __syncthreads();           // staged & visible
        }
    }
}

extern "C" void kernel_launch(void* const* d_in, const int* in_sizes, int n_in,
                              void* d_out, int out_size, void* d_ws, size_t ws_size,
                              hipStream_t stream) {
    const float* x    = (const float*)d_in[0];
    const float* off  = (const float*)d_in[1];
    const float* w    = (const float*)d_in[2];
    const float* bias = (const float*)d_in[3];
    float* out        = (float*)d_out;
    dim3 grid(H_ / TH, B_, CSPLIT);
    deform_dw_conv<<<grid, NT, 0, stream>>>(x, off, w, bias, out);
}